// Round 5
// baseline (970.435 us; speedup 1.0000x reference)
//
#include <hip/hip_runtime.h>
#include <hip/hip_bf16.h>

// Problem constants
#define S 2048
#define D 768
#define H 12
#define HD 64
#define FF 3072
#define NL 6
#define WIN 128
#define PADIDX 1

typedef __hip_bfloat16 bf16;
typedef __attribute__((ext_vector_type(8))) __bf16 bf16x8;
typedef __attribute__((ext_vector_type(4))) float f32x4;
typedef __attribute__((ext_vector_type(8))) unsigned short u16x8;

__device__ __forceinline__ unsigned short f2bfu(float f) {
    bf16 b = __float2bfloat16(f);
    return *(unsigned short*)&b;
}

// async global->LDS, 16B per lane. LDS base must be wave-uniform; global addr may vary per lane.
__device__ __forceinline__ void g2l16(const bf16* g, bf16* l) {
    __builtin_amdgcn_global_load_lds((__attribute__((address_space(1))) void*)(g),
                                     (__attribute__((address_space(3))) void*)(l), 16, 0, 0);
}

// ---------------- positions (fairseq make_positions) ----------------
__global__ void positions_kernel(const int* __restrict__ tokens, int* __restrict__ positions) {
    __shared__ int sums[256];
    int t = threadIdx.x;
    int np[8]; int loc = 0;
    for (int i = 0; i < 8; i++) { np[i] = (tokens[t * 8 + i] != PADIDX) ? 1 : 0; loc += np[i]; }
    sums[t] = loc;
    __syncthreads();
    for (int off = 1; off < 256; off <<= 1) {
        int u = (t >= off) ? sums[t - off] : 0;
        __syncthreads();
        sums[t] += u;
        __syncthreads();
    }
    int run = (t > 0) ? sums[t - 1] : 0;
    for (int i = 0; i < 8; i++) {
        run += np[i];
        positions[t * 8 + i] = np[i] ? (PADIDX + run) : PADIDX;
    }
}

// ---------------- embedding ----------------
__global__ void embed_kernel(const int* __restrict__ tokens, const int* __restrict__ seg,
                             const int* __restrict__ positions,
                             const float* __restrict__ emb, const float* __restrict__ pemb,
                             const float* __restrict__ semb,
                             float* __restrict__ h, bf16* __restrict__ h_bf) {
    int s = blockIdx.x, t = threadIdx.x;
    int tok = tokens[s];
    int pos = positions[s];
    int sg = seg[s];
    bool pad = (tok == PADIDX);
    for (int i = 0; i < 3; i++) {
        int c = t + i * 256;
        float val = emb[(size_t)tok * D + c] + pemb[(size_t)pos * D + c] + semb[(size_t)sg * D + c];
        if (pad) val = 0.0f;
        h[(size_t)s * D + c] = val;
        h_bf[(size_t)s * D + c] = __float2bfloat16(val);
    }
}

// ---------------- fp32 [K,N] -> bf16 [N,K] transpose+convert ----------------
__global__ void transpose_convert(const float* __restrict__ src, bf16* __restrict__ dst,
                                  int K, int N, long srcLS, long dstLS) {
    src += (long)blockIdx.z * srcLS;
    dst += (long)blockIdx.z * dstLS;
    __shared__ float tile[64][65];
    int k0 = blockIdx.x * 64, n0 = blockIdx.y * 64;
    int t = threadIdx.x;
    for (int i = t; i < 4096; i += 256) {
        int r = i >> 6, c = i & 63;
        tile[r][c] = src[(long)(k0 + r) * N + n0 + c];
    }
    __syncthreads();
    for (int i = t; i < 4096; i += 256) {
        int r = i >> 6, c = i & 63;
        dst[(long)(n0 + r) * K + k0 + c] = __float2bfloat16(tile[c][r]);
    }
}

// ---------------- GEMM 64x128 tile: C[M,N] = A[M,K] @ Bt[N,K]^T (+epilogue) ----------------
// LDS k-oct XOR swizzle keeps fragment ds_read_b128 2-way (free).
// MODE 0: qkv  -> (acc + bias{q,k,v}[col]) * (col<768 ? 0.125 : 1), bf16 out
// MODE 1: partial fp32 out (outF + z*M*N); bias0 added only on split z==0
// MODE 2: ff1  -> relu(acc + bias0[col]), bf16 out
template <int MODE>
__global__ __launch_bounds__(256, 4) void gemm64(
    const bf16* __restrict__ A, const bf16* __restrict__ Bt,
    const float* __restrict__ bias0, const float* __restrict__ bias1, const float* __restrict__ bias2,
    float* __restrict__ outF, bf16* __restrict__ outB, int M, int N, int K, int klen) {
    __shared__ __align__(16) bf16 As[64 * 32];
    __shared__ __align__(16) bf16 Bs[128 * 32];
    int t = threadIdx.x;
    int lane = t & 63, w = t >> 6;
    int m0 = blockIdx.x * 64, n0 = blockIdx.y * 128;
    int kbase = blockIdx.z * klen;
    int wm = (w & 1) * 32, wn = (w >> 1) * 64;
    int qd = lane >> 4, l16 = lane & 15;

    f32x4 acc[2][4] = {};

    int i1 = t + 256;
    int oA  = ((t & 3) ^ ((t >> 3) & 3)) * 8;
    int oB1 = ((i1 & 3) ^ ((i1 >> 3) & 3)) * 8;
    const bf16* Ag  = A  + (size_t)(m0 + (t >> 2)) * K + kbase + oA;
    const bf16* Bg0 = Bt + (size_t)(n0 + (t >> 2)) * K + kbase + oA;
    const bf16* Bg1 = Bt + (size_t)(n0 + (i1 >> 2)) * K + kbase + oB1;
    bf16* Al  = As + (size_t)(t & ~63) * 8;
    bf16* Bl0 = Bs + (size_t)(t & ~63) * 8;
    bf16* Bl1 = Bs + (size_t)(256 + (t & ~63)) * 8;

    int soct = (qd ^ ((l16 >> 1) & 3)) * 8;

    int nkt = klen >> 5;
    for (int kt = 0; kt < nkt; ++kt) {
        int ko = kt * 32;
        g2l16(Ag + ko, Al);
        g2l16(Bg0 + ko, Bl0);
        g2l16(Bg1 + ko, Bl1);
        __syncthreads();
        bf16x8 aF[2], bF[4];
#pragma unroll
        for (int mi = 0; mi < 2; mi++) aF[mi] = *(const bf16x8*)&As[(wm + mi * 16 + l16) * 32 + soct];
#pragma unroll
        for (int ni = 0; ni < 4; ni++) bF[ni] = *(const bf16x8*)&Bs[(wn + ni * 16 + l16) * 32 + soct];
#pragma unroll
        for (int mi = 0; mi < 2; mi++)
#pragma unroll
            for (int ni = 0; ni < 4; ni++)
                acc[mi][ni] = __builtin_amdgcn_mfma_f32_16x16x32_bf16(aF[mi], bF[ni], acc[mi][ni], 0, 0, 0);
        __syncthreads();
    }

#pragma unroll
    for (int ni = 0; ni < 4; ni++) {
        int col = n0 + wn + ni * 16 + l16;
        float bb;
        if (MODE == 0) bb = (col < 768) ? bias0[col] : ((col < 1536) ? bias1[col - 768] : bias2[col - 1536]);
        else if (MODE == 1) bb = (blockIdx.z == 0) ? bias0[col] : 0.0f;
        else bb = bias0[col];
#pragma unroll
        for (int mi = 0; mi < 2; mi++) {
            int row = m0 + wm + mi * 16 + qd * 4;
#pragma unroll
            for (int r = 0; r < 4; r++) {
                float v = acc[mi][ni][r] + bb;
                if (MODE == 0) {
                    if (col < 768) v *= 0.125f;  // 1/sqrt(64)
                    outB[(size_t)(row + r) * N + col] = __float2bfloat16(v);
                } else if (MODE == 1) {
                    outF[(size_t)blockIdx.z * M * N + (size_t)(row + r) * N + col] = v;
                } else {
                    v = fmaxf(v, 0.0f);
                    outB[(size_t)(row + r) * N + col] = __float2bfloat16(v);
                }
            }
        }
    }
}

// ---------------- chunked online-softmax MFMA windowed attention ----------------
// One block = (head, 32-query tile); window <=288 keys in 2 chunks of <=160.
// LDS ~45 KB -> 3 blocks/CU. K chunk staged via global_load_lds (XOR-oct swizzle).
#define KC 160     // keys per chunk
#define VSTR2 168  // V^T / P row stride (2-way bank alias = free)
__global__ __launch_bounds__(256, 3) void attn_kernel(const bf16* __restrict__ qkv,
                                                      const int* __restrict__ tokens,
                                                      const float* __restrict__ relb,
                                                      bf16* __restrict__ out) {
    const int q0 = blockIdx.x * 32;
    const int h = blockIdx.y;
    const int t = threadIdx.x;
    const int lane = t & 63, w = t >> 6;
    const int l16 = lane & 15, qd = lane >> 4;
    const int klo = max(0, q0 - WIN);
    const int khi = min(S - 1, q0 + 31 + WIN);
    const int nk = khi - klo + 1;           // always a multiple of 32, in [160, 288]

    __shared__ __align__(16) unsigned short KB[KC * 64];     // K chunk [key][64] swizzled; reused as P [32][VSTR2]
    __shared__ __align__(16) unsigned short VT[64 * VSTR2];  // V^T chunk [d][key]
    __shared__ float rbS[260];
    __shared__ float wmaxS[4][32];
    __shared__ float wsumS[4][32];
    __shared__ float mS[2][32];              // ping-pong running max
    __shared__ char kmS[320];

    const unsigned short* qkvu = (const unsigned short*)qkv;

    // tables (ordered by the post-staging barrier of chunk 0)
    for (int idx = t; idx < 260; idx += 256) {
        int dd = idx - 129;
        float bv = -1e30f;
        if (dd >= -128 && dd <= 128) {
            int ni = dd, ret = 0;
            if (ni < 0) { ret = 16; ni = -ni; }
            int val;
            if (ni < 8) val = ni;
            else {
                int m;
                if (ni < 12) m = 0; else if (ni < 16) m = 1; else if (ni < 23) m = 2;
                else if (ni < 32) m = 3; else if (ni < 46) m = 4; else if (ni < 64) m = 5;
                else if (ni < 91) m = 6; else if (ni < 128) m = 7; else m = 8;
                val = 8 + m;
                if (val > 15) val = 15;
            }
            bv = relb[(ret + val) * H + h];
        }
        rbS[idx] = bv;
    }
    for (int idx = t; idx < 320; idx += 256) {
        int key = klo + idx;
        kmS[idx] = (key < S && tokens[key] != PADIDX) ? 0 : 1;
    }
    if (t < 32) mS[0][t] = -3e38f;

    // Q fragments (q pre-scaled by 1/8 in QKV epilogue)
    bf16x8 Qf[2][2];
#pragma unroll
    for (int qt2 = 0; qt2 < 2; qt2++)
#pragma unroll
        for (int ko = 0; ko < 2; ko++)
            Qf[qt2][ko] = *(const bf16x8*)(qkvu + (size_t)(q0 + qt2 * 16 + l16) * 2304 + h * 64 + ko * 32 + qd * 8);

    f32x4 o0 = {}, o1 = {};
    float lrow[4] = {0.f, 0.f, 0.f, 0.f};
    const int qt = w & 1, dt0 = (w >> 1) * 2;
    const int qmk = q0 - klo;
    const int rr8 = l16 & 7;

    for (int c = 0; c < 2; ++c) {
        const int kbase = c * KC;
        const int kcnt = min(nk - kbase, KC);
        if (kcnt <= 0) break;
        if (c) __syncthreads();  // prev-chunk PV reads of KB/VT must finish

        // ---- stage K chunk via global_load_lds, XOR-oct swizzle ----
        {
            const int rsub = lane >> 3;              // 0..7 (row within 8-row group)
            const int o = (lane & 7) ^ rsub;         // swizzled global oct (row&7 == rsub)
            const int wr0 = w * 40;                  // 40 % 8 == 0 keeps row&7 == rsub
#pragma unroll
            for (int j = 0; j < 5; ++j) {
                int row = wr0 + j * 8 + rsub;
                int ksrc = min(klo + kbase + row, S - 1);
                g2l16((const bf16*)(qkvu + (size_t)ksrc * 2304 + 768 + h * 64 + o * 8),
                      (bf16*)&KB[(wr0 + j * 8) * 64]);
            }
        }
        // ---- stage V^T (transpose in flight) ----
#pragma unroll
        for (int jj = 0; jj < 5; ++jj) {
            int i = jj * 256 + t;                    // 1280 tasks: (oct, key)
            int oct = i / KC;
            int key = i - oct * KC;
            int ksrc = min(klo + kbase + key, S - 1);
            u16x8 v = *(const u16x8*)(qkvu + (size_t)ksrc * 2304 + 1536 + h * 64 + oct * 8);
#pragma unroll
            for (int u = 0; u < 8; ++u) VT[(oct * 8 + u) * VSTR2 + key] = v[u];
        }
        __syncthreads();

        // ---- QK^T: wave w owns key-tiles kt = w + 4j ----
        const int kt16 = kcnt >> 4;
        f32x4 acc[2][3] = {};
#pragma unroll
        for (int j = 0; j < 3; ++j) {
            int kt = w + 4 * j;
            if (kt < kt16) {
                const unsigned short* kr = &KB[(kt * 16 + l16) * 64];
                bf16x8 b0 = *(const bf16x8*)&kr[(qd ^ rr8) * 8];
                bf16x8 b1 = *(const bf16x8*)&kr[((4 | qd) ^ rr8) * 8];
#pragma unroll
                for (int q2 = 0; q2 < 2; ++q2) {
                    acc[q2][j] = __builtin_amdgcn_mfma_f32_16x16x32_bf16(Qf[q2][0], b0, acc[q2][j], 0, 0, 0);
                    acc[q2][j] = __builtin_amdgcn_mfma_f32_16x16x32_bf16(Qf[q2][1], b1, acc[q2][j], 0, 0, 0);
                }
            }
        }

        // ---- bias + mask + chunk row-max ----
        float rmax[2][4];
#pragma unroll
        for (int q2 = 0; q2 < 2; ++q2)
#pragma unroll
            for (int r = 0; r < 4; ++r) rmax[q2][r] = -3e38f;
#pragma unroll
        for (int j = 0; j < 3; ++j) {
            int kt = w + 4 * j;
            if (kt < kt16) {
                int g = kbase + kt * 16 + l16;
                float km = kmS[g] ? -1e30f : 0.0f;
#pragma unroll
                for (int q2 = 0; q2 < 2; ++q2)
#pragma unroll
                    for (int r = 0; r < 4; ++r) {
                        int dd = qmk + q2 * 16 + qd * 4 + r - g;
                        dd = min(129, max(-129, dd));
                        float sc = acc[q2][j][r] + rbS[dd + 129] + km;
                        acc[q2][j][r] = sc;
                        rmax[q2][r] = fmaxf(rmax[q2][r], sc);
                    }
            }
        }
#pragma unroll
        for (int m = 1; m < 16; m <<= 1)
#pragma unroll
            for (int q2 = 0; q2 < 2; ++q2)
#pragma unroll
                for (int r = 0; r < 4; ++r)
                    rmax[q2][r] = fmaxf(rmax[q2][r], __shfl_xor(rmax[q2][r], m));
        if (l16 == 0) {
#pragma unroll
            for (int q2 = 0; q2 < 2; ++q2)
#pragma unroll
                for (int r = 0; r < 4; ++r) wmaxS[w][q2 * 16 + qd * 4 + r] = rmax[q2][r];
        }
        __syncthreads();

        // ---- online-softmax update + exp + P (into KB) + partial sums ----
        float mnew[2][4], alpha[2][4];
#pragma unroll
        for (int q2 = 0; q2 < 2; ++q2)
#pragma unroll
            for (int r = 0; r < 4; ++r) {
                int row = q2 * 16 + qd * 4 + r;
                float cm = fmaxf(fmaxf(wmaxS[0][row], wmaxS[1][row]), fmaxf(wmaxS[2][row], wmaxS[3][row]));
                float mp = mS[c & 1][row];
                float mn = fmaxf(mp, cm);
                mnew[q2][r] = mn;
                alpha[q2][r] = __expf(mp - mn);
            }
        float ls[2][4] = {};
#pragma unroll
        for (int j = 0; j < 3; ++j) {
            int kt = w + 4 * j;
            if (kt < kt16) {
#pragma unroll
                for (int q2 = 0; q2 < 2; ++q2)
#pragma unroll
                    for (int r = 0; r < 4; ++r) {
                        float p = __expf(acc[q2][j][r] - mnew[q2][r]);
                        ls[q2][r] += p;
                        KB[(q2 * 16 + qd * 4 + r) * VSTR2 + kt * 16 + l16] = f2bfu(p);
                    }
            }
        }
#pragma unroll
        for (int m = 1; m < 16; m <<= 1)
#pragma unroll
            for (int q2 = 0; q2 < 2; ++q2)
#pragma unroll
                for (int r = 0; r < 4; ++r) ls[q2][r] += __shfl_xor(ls[q2][r], m);
        if (l16 == 0) {
#pragma unroll
            for (int q2 = 0; q2 < 2; ++q2)
#pragma unroll
                for (int r = 0; r < 4; ++r) wsumS[w][q2 * 16 + qd * 4 + r] = ls[q2][r];
        }
        if (w == 0 && l16 == 0) {
#pragma unroll
            for (int q2 = 0; q2 < 2; ++q2)
#pragma unroll
                for (int r = 0; r < 4; ++r) mS[(c + 1) & 1][q2 * 16 + qd * 4 + r] = mnew[q2][r];
        }
        __syncthreads();

        // ---- PV: wave w -> (qt = w&1, d-tiles dt0, dt0+1), rescale-accumulate ----
        const int kk32 = kcnt >> 5;
        f32x4 pv0 = {}, pv1 = {};
        for (int kk = 0; kk < kk32; ++kk) {
            bf16x8 aP = *(const bf16x8*)&KB[(qt * 16 + l16) * VSTR2 + kk * 32 + qd * 8];
            bf16x8 v0 = *(const bf16x8*)&VT[(dt0 * 16 + l16) * VSTR2 + kk * 32 + qd * 8];
            bf16x8 v1 = *(const bf16x8*)&VT[((dt0 + 1) * 16 + l16) * VSTR2 + kk * 32 + qd * 8];
            pv0 = __builtin_amdgcn_mfma_f32_16x16x32_bf16(aP, v0, pv0, 0, 0, 0);
            pv1 = __builtin_amdgcn_mfma_f32_16x16x32_bf16(aP, v1, pv1, 0, 0, 0);
        }
#pragma unroll
        for (int r = 0; r < 4; ++r) {
            int row = qt * 16 + qd * 4 + r;
            float a = alpha[qt][r];
            float tot = wsumS[0][row] + wsumS[1][row] + wsumS[2][row] + wsumS[3][row];
            lrow[r] = lrow[r] * a + tot;
            o0[r] = o0[r] * a + pv0[r];
            o1[r] = o1[r] * a + pv1[r];
        }
    }

#pragma unroll
    for (int r = 0; r < 4; ++r) {
        int row = qt * 16 + qd * 4 + r;
        float inv = 1.0f / lrow[r];
        size_t ob = (size_t)(q0 + row) * D + h * 64;
        out[ob + dt0 * 16 + l16] = __float2bfloat16(o0[r] * inv);
        out[ob + (dt0 + 1) * 16 + l16] = __float2bfloat16(o1[r] * inv);
    }
}

// ---------------- residual + NP split-K partials + layernorm ----------------
template <int NP>
__global__ __launch_bounds__(256) void ln_kernel(const float* __restrict__ x, const float* __restrict__ parts,
                                                 const float* __restrict__ sc, const float* __restrict__ bi,
                                                 float* __restrict__ out, bf16* __restrict__ out_bf) {
    int row = blockIdx.x, t = threadIdx.x;
    float v[3];
    float lsum = 0.0f, lsq = 0.0f;
#pragma unroll
    for (int i = 0; i < 3; i++) {
        int c = t + i * 256;
        size_t idx = (size_t)row * D + c;
        float val = x[idx];
#pragma unroll
        for (int p = 0; p < NP; p++) val += parts[(size_t)p * S * D + idx];
        v[i] = val; lsum += val; lsq += val * val;
    }
#pragma unroll
    for (int off = 32; off; off >>= 1) { lsum += __shfl_down(lsum, off); lsq += __shfl_down(lsq, off); }
    __shared__ float s1[4], s2[4];
    if ((t & 63) == 0) { s1[t >> 6] = lsum; s2[t >> 6] = lsq; }
    __syncthreads();
    float tot = s1[0] + s1[1] + s1[2] + s1[3];
    float tot2 = s2[0] + s2[1] + s2[2] + s2[3];
    float mean = tot * (1.0f / 768.0f);
    float var = tot2 * (1.0f / 768.0f) - mean * mean;
    float rstd = rsqrtf(var + 1e-5f);
#pragma unroll
    for (int i = 0; i < 3; i++) {
        int c = t + i * 256;
        float y = (v[i] - mean) * rstd * sc[c] + bi[c];
        out[(size_t)row * D + c] = y;
        out_bf[(size_t)row * D + c] = __float2bfloat16(y);
    }
}

extern "C" void kernel_launch(void* const* d_in, const int* in_sizes, int n_in,
                              void* d_out, int out_size, void* d_ws, size_t ws_size,
                              hipStream_t stream) {
    const int* tokens = (const int*)d_in[0];
    const int* seg = (const int*)d_in[1];
    const float* emb = (const float*)d_in[2];
    const float* pemb = (const float*)d_in[3];
    const float* semb = (const float*)d_in[4];
    const float* relb = (const float*)d_in[5];
    const float* Wq = (const float*)d_in[6];  const float* bq = (const float*)d_in[7];
    const float* Wk = (const float*)d_in[8];  const float* bk = (const float*)d_in[9];
    const float* Wv = (const float*)d_in[10]; const float* bv = (const float*)d_in[11];
    const float* Wo = (const float*)d_in[12]; const float* bo = (const float*)d_in[13];
    const float* ln1s = (const float*)d_in[14]; const float* ln1b = (const float*)d_in[15];
    const float* W1 = (const float*)d_in[16]; const float* b1 = (const float*)d_in[17];
    const float* W2 = (const float*)d_in[18]; const float* b2 = (const float*)d_in[19];
    const float* ln2s = (const float*)d_in[20]; const float* ln2b = (const float*)d_in[21];

    char* base = (char*)d_ws;
    size_t off = 0;
    auto take = [&](size_t bytes) -> char* {
        char* p = base + off;
        off = (off + bytes + 255) & ~(size_t)255;
        return p;
    };
    int* positions = (int*)take((size_t)S * 4);
    float* h       = (float*)take((size_t)S * D * 4);
    bf16* h_bf     = (bf16*)take((size_t)S * D * 2);
    float* parts   = (float*)take((size_t)4 * S * D * 4);
    bf16* qkv      = (bf16*)take((size_t)S * 2304 * 2);
    bf16* attnO    = (bf16*)take((size_t)S * D * 2);
    bf16* ff1      = (bf16*)take((size_t)S * FF * 2);
    bf16* Wqkv_t   = (bf16*)take((size_t)NL * 2304 * 768 * 2);
    bf16* Wo_t     = (bf16*)take((size_t)NL * 768 * 768 * 2);
    bf16* W1_t     = (bf16*)take((size_t)NL * 3072 * 768 * 2);
    bf16* W2_t     = (bf16*)take((size_t)NL * 768 * 3072 * 2);
    (void)ws_size; (void)n_in; (void)in_sizes;

    positions_kernel<<<1, 256, 0, stream>>>(tokens, positions);
    embed_kernel<<<S, 256, 0, stream>>>(tokens, seg, positions, emb, pemb, semb, h, h_bf);

    transpose_convert<<<dim3(12, 12, NL), 256, 0, stream>>>(Wq, Wqkv_t, 768, 768, 768L * 768, 2304L * 768);
    transpose_convert<<<dim3(12, 12, NL), 256, 0, stream>>>(Wk, Wqkv_t + 768L * 768, 768, 768, 768L * 768, 2304L * 768);
    transpose_convert<<<dim3(12, 12, NL), 256, 0, stream>>>(Wv, Wqkv_t + 1536L * 768, 768, 768, 768L * 768, 2304L * 768);
    transpose_convert<<<dim3(12, 12, NL), 256, 0, stream>>>(Wo, Wo_t, 768, 768, 768L * 768, 768L * 768);
    transpose_convert<<<dim3(12, 48, NL), 256, 0, stream>>>(W1, W1_t, 768, 3072, 768L * 3072, 3072L * 768);
    transpose_convert<<<dim3(48, 12, NL), 256, 0, stream>>>(W2, W2_t, 3072, 768, 3072L * 768, 768L * 3072);

    for (int l = 0; l < NL; l++) {
        gemm64<0><<<dim3(32, 18, 1), 256, 0, stream>>>(h_bf, Wqkv_t + (size_t)l * 2304 * 768,
                                                       bq + l * 768, bk + l * 768, bv + l * 768,
                                                       nullptr, qkv, S, 2304, 768, 768);
        attn_kernel<<<dim3(S / 32, H), 256, 0, stream>>>(qkv, tokens, relb, attnO);
        gemm64<1><<<dim3(32, 6, 2), 256, 0, stream>>>(attnO, Wo_t + (size_t)l * 768 * 768,
                                                      bo + l * 768, nullptr, nullptr,
                                                      parts, nullptr, S, 768, 768, 384);
        ln_kernel<2><<<S, 256, 0, stream>>>(h, parts, ln1s + l * 768, ln1b + l * 768, h, h_bf);
        gemm64<2><<<dim3(32, 24, 1), 256, 0, stream>>>(h_bf, W1_t + (size_t)l * 3072 * 768,
                                                       b1 + l * 3072, nullptr, nullptr,
                                                       nullptr, ff1, S, 3072, 768, 768);
        gemm64<1><<<dim3(32, 6, 4), 256, 0, stream>>>(ff1, W2_t + (size_t)l * 768 * 3072,
                                                      b2 + l * 768, nullptr, nullptr,
                                                      parts, nullptr, S, 768, 3072, 768);
        ln_kernel<4><<<S, 256, 0, stream>>>(h, parts, ln2s + l * 768, ln2b + l * 768, h, h_bf);
    }
    hipMemcpyAsync(d_out, h, (size_t)out_size * 4, hipMemcpyDeviceToDevice, stream);
}